// Round 1
// baseline (926.495 us; speedup 1.0000x reference)
//
#include <hip/hip_runtime.h>

typedef unsigned short us;
typedef __bf16 v8bf __attribute__((ext_vector_type(8)));
typedef float v4f __attribute__((ext_vector_type(4)));
typedef us us4v __attribute__((ext_vector_type(4)));
typedef us us8v __attribute__((ext_vector_type(8)));
typedef float f4v __attribute__((ext_vector_type(4)));

#define SCALE 0.08838834764831845f

__device__ __forceinline__ us f2bf(float f) {
  unsigned u = __builtin_bit_cast(unsigned, f);
  u += 0x7fffu + ((u >> 16) & 1u);
  return (us)(u >> 16);
}
__device__ __forceinline__ float bf2f(us h) {
  unsigned u = ((unsigned)h) << 16;
  return __builtin_bit_cast(float, u);
}

typedef const __attribute__((address_space(1))) void* gas_t;
typedef __attribute__((address_space(3))) void* las_t;
#define GLD16(gp, lp) __builtin_amdgcn_global_load_lds((gas_t)(gp), (las_t)(lp), 16, 0, 0)

// ---------------- fp32 -> bf16 cast (vectorized, grid-stride) ----------------
__global__ void cast_kernel(const float* __restrict__ in, us* __restrict__ out, int n) {
  int stride = gridDim.x * blockDim.x * 4;
  for (int i = (blockIdx.x * blockDim.x + threadIdx.x) * 4; i < n; i += stride) {
    f4v f = *(const f4v*)(in + i);
    us4v o;
#pragma unroll
    for (int j = 0; j < 4; ++j) o[j] = f2bf(f[j]);
    *(us4v*)(out + i) = o;
  }
}

// ---------------- GEMM: C = A @ Bt^T  (A[M,K], Bt[N,K] both row-major bf16) ----------------
// m97 structure: 128x128 tile, BK=32, 4 waves, each wave 64x64 (acc 4x4 of 16x16x32).
// EPI 0: write fp32 to outF[M,N]. EPI 1: scatter bf16 Q/K/V into [b][h][s][d].
template <int EPI>
__global__ __launch_bounds__(256, 2) void gemm_bt(
    const us* __restrict__ A, const us* __restrict__ Bt, int M, int N, int K,
    float* __restrict__ outF, us* __restrict__ outQ, us* __restrict__ outK,
    us* __restrict__ outV) {
  __shared__ us As[4096];  // 128 x 32
  __shared__ us Bs[4096];
  const int tid = threadIdx.x;
  const int lane = tid & 63;
  const int w = tid >> 6;
  const int bn = blockIdx.x, bm = blockIdx.y;
  const int row0 = bm * 128, col0 = bn * 128;
  const int wm = w >> 1, wn = w & 1;
  const int lr = lane & 15, lg = lane >> 4;

  v4f acc[4][4];
#pragma unroll
  for (int m = 0; m < 4; ++m)
#pragma unroll
    for (int n = 0; n < 4; ++n)
#pragma unroll
      for (int j = 0; j < 4; ++j) acc[m][n][j] = 0.f;

  // staging chunks: 512 chunks of 16B per matrix; wave w inst i covers chunks (i*4+w)*64 + lane
  const int c0 = w * 64 + lane;
  const int c1 = 256 + w * 64 + lane;
  const us* Ag0 = A + (row0 + (c0 >> 2)) * K + (c0 & 3) * 8;
  const us* Ag1 = A + (row0 + (c1 >> 2)) * K + (c1 & 3) * 8;
  const us* Bg0 = Bt + (col0 + (c0 >> 2)) * K + (c0 & 3) * 8;
  const us* Bg1 = Bt + (col0 + (c1 >> 2)) * K + (c1 & 3) * 8;
  us* lA0 = &As[w * 512];
  us* lA1 = &As[2048 + w * 512];
  us* lB0 = &Bs[w * 512];
  us* lB1 = &Bs[2048 + w * 512];

  for (int kt = 0; kt < K; kt += 32) {
    __syncthreads();
    GLD16(Ag0 + kt, lA0);
    GLD16(Ag1 + kt, lA1);
    GLD16(Bg0 + kt, lB0);
    GLD16(Bg1 + kt, lB1);
    __syncthreads();
    v8bf a[4], b[4];
#pragma unroll
    for (int m = 0; m < 4; ++m)
      a[m] = *(const v8bf*)(&As[(wm * 64 + m * 16 + lr) * 32 + lg * 8]);
#pragma unroll
    for (int n = 0; n < 4; ++n)
      b[n] = *(const v8bf*)(&Bs[(wn * 64 + n * 16 + lr) * 32 + lg * 8]);
#pragma unroll
    for (int m = 0; m < 4; ++m)
#pragma unroll
      for (int n = 0; n < 4; ++n)
        acc[m][n] = __builtin_amdgcn_mfma_f32_16x16x32_bf16(a[m], b[n], acc[m][n], 0, 0, 0);
  }

  if (EPI == 0) {
#pragma unroll
    for (int m = 0; m < 4; ++m) {
#pragma unroll
      for (int r = 0; r < 4; ++r) {
        int row = row0 + wm * 64 + m * 16 + lg * 4 + r;
#pragma unroll
        for (int n = 0; n < 4; ++n) {
          int col = col0 + wn * 64 + n * 16 + lr;
          outF[(long)row * N + col] = acc[m][n][r];
        }
      }
    }
  } else {
    // tile columns = exactly one head of one of {Q,K,V}
    const int which = bn >> 5;
    const int h = bn & 31;
    us* base = (which == 0) ? outQ : ((which == 1) ? outK : outV);
#pragma unroll
    for (int m = 0; m < 4; ++m) {
#pragma unroll
      for (int r = 0; r < 4; ++r) {
        int trow = row0 + wm * 64 + m * 16 + lg * 4 + r;
        int b2 = trow >> 10, spos = trow & 1023;
        us* rowp = base + ((b2 * 32 + h) * 1024 + spos) * 128;
#pragma unroll
        for (int n = 0; n < 4; ++n) {
          int d = wn * 64 + n * 16 + lr;
          rowp[d] = f2bf(acc[m][n][r]);
        }
      }
    }
  }
}

// ---------------- RoPE in place on Q and K ([b][h][s][d] bf16) ----------------
__global__ void rope_kernel(us* __restrict__ Qb, us* __restrict__ Kb,
                            const float* __restrict__ cosT, const float* __restrict__ sinT) {
  int idx = blockIdx.x * blockDim.x + threadIdx.x;  // 2 * 131072 rows * 16 thr/row
  int pj = idx & 15;
  int rowid = idx >> 4;
  us* P = (rowid < 131072) ? Qb : Kb;
  int r = rowid & 131071;
  int bh = r >> 10, spos = r & 1023;
  int b = bh >> 5;
  int t = b * 1024 + spos;  // cos/sin row index (position = s)
  int d0 = pj * 4;
  us* p = P + (long)r * 128;
  us4v x1 = *(const us4v*)(p + d0);
  us4v x2 = *(const us4v*)(p + d0 + 64);
  f4v c = *(const f4v*)(cosT + t * 64 + d0);
  f4v s = *(const f4v*)(sinT + t * 64 + d0);
  us4v y1, y2;
#pragma unroll
  for (int j = 0; j < 4; ++j) {
    float a = bf2f(x1[j]), bv = bf2f(x2[j]);
    y1[j] = f2bf(a * c[j] - bv * s[j]);
    y2[j] = f2bf(bv * c[j] + a * s[j]);
  }
  *(us4v*)(p + d0) = y1;
  *(us4v*)(p + d0 + 64) = y2;
}

// ---------------- V transpose: [bh][s][d] -> [bh][d][s] ----------------
__global__ void transpose_v(const us* __restrict__ V, us* __restrict__ Vt) {
  __shared__ us tile[64][66];
  const int tid = threadIdx.x;
  const int s0 = blockIdx.x * 64;
  const int d0 = blockIdx.y * 64;
  const int bh = blockIdx.z;
  const us* Vb = V + (long)bh * 131072;
  us* Vtb = Vt + (long)bh * 131072;
  const int rr = tid >> 2, cq = tid & 3;
  us8v v0 = *(const us8v*)(Vb + (s0 + rr) * 128 + d0 + cq * 16);
  us8v v1 = *(const us8v*)(Vb + (s0 + rr) * 128 + d0 + cq * 16 + 8);
#pragma unroll
  for (int j = 0; j < 8; ++j) {
    tile[rr][cq * 16 + j] = v0[j];
    tile[rr][cq * 16 + 8 + j] = v1[j];
  }
  __syncthreads();
  us8v o0, o1;
#pragma unroll
  for (int j = 0; j < 8; ++j) {
    o0[j] = tile[cq * 16 + j][rr];
    o1[j] = tile[cq * 16 + 8 + j][rr];
  }
  *(us8v*)(Vtb + (d0 + rr) * 1024 + s0 + cq * 16) = o0;
  *(us8v*)(Vtb + (d0 + rr) * 1024 + s0 + cq * 16 + 8) = o1;
}

// ---------------- causal flash attention ----------------
// grid (8 qtiles, 128 bh). 4 waves x 32 q-rows. KV tile = 64.
// K LDS [64key][128d], Vt LDS [128d][64key], both 16B-chunk XOR-swizzled
// (linear global_load_lds dest + inverse-swizzled global source, swizzled ds_read).
__global__ __launch_bounds__(256, 2) void attn_kernel(
    const us* __restrict__ Q, const us* __restrict__ Kg,
    const us* __restrict__ Vt, us* __restrict__ Out) {
  __shared__ us Ks[8192];
  __shared__ us Vs[8192];
  __shared__ us Ps[4 * 2048];  // per-wave P[32q][64k], swizzled
  const int tid = threadIdx.x, lane = tid & 63, w = tid >> 6;
  const int qt = (int)gridDim.x - 1 - (int)blockIdx.x;  // heavy blocks first
  const int bh = blockIdx.y;
  const int lr = lane & 15, lg = lane >> 4;
  const int q0 = qt * 128 + w * 32;

  // Q fragments held in registers for the whole kernel
  v8bf qf[2][4];
  const us* Qb = Q + ((long)bh * 1024 + q0) * 128;
#pragma unroll
  for (int mq = 0; mq < 2; ++mq)
#pragma unroll
    for (int ks = 0; ks < 4; ++ks)
      qf[mq][ks] = *(const v8bf*)(Qb + (mq * 16 + lr) * 128 + ks * 32 + lg * 8);

  float m_run[2][4], l_run[2][4];
  v4f o_acc[2][8];
#pragma unroll
  for (int mq = 0; mq < 2; ++mq) {
#pragma unroll
    for (int r = 0; r < 4; ++r) {
      m_run[mq][r] = -1e30f;
      l_run[mq][r] = 0.f;
    }
#pragma unroll
    for (int nd = 0; nd < 8; ++nd)
#pragma unroll
      for (int j = 0; j < 4; ++j) o_acc[mq][nd][j] = 0.f;
  }

  const us* Kbase = Kg + (long)bh * 131072;
  const us* Vbase = Vt + (long)bh * 131072;
  us* Pw = &Ps[w * 2048];

  const int nkt = 2 * qt + 2;
  for (int kt = 0; kt < nkt; ++kt) {
    __syncthreads();
#pragma unroll
    for (int i = 0; i < 4; ++i) {  // K tile: rows of 256B = 16 chunks
      int c = (i * 4 + w) * 64 + lane;
      int rk = c >> 4, pc = c & 15;
      GLD16(Kbase + (kt * 64 + rk) * 128 + ((pc ^ (rk & 7)) * 8), &Ks[(i * 4 + w) * 512]);
    }
#pragma unroll
    for (int i = 0; i < 4; ++i) {  // Vt tile: rows of 128B = 8 chunks
      int c = (i * 4 + w) * 64 + lane;
      int dd = c >> 3, pc = c & 7;
      GLD16(Vbase + dd * 1024 + kt * 64 + ((pc ^ (dd & 7)) * 8), &Vs[(i * 4 + w) * 512]);
    }
    __syncthreads();

    // S = Q @ K^T
    v4f sacc[2][4];
#pragma unroll
    for (int mq = 0; mq < 2; ++mq)
#pragma unroll
      for (int nk = 0; nk < 4; ++nk)
#pragma unroll
        for (int j = 0; j < 4; ++j) sacc[mq][nk][j] = 0.f;
#pragma unroll
    for (int nk = 0; nk < 4; ++nk) {
      int key = nk * 16 + lr;
#pragma unroll
      for (int ks = 0; ks < 4; ++ks) {
        int pc = (ks * 4 + lg) ^ (key & 7);
        v8bf kf = *(const v8bf*)(&Ks[key * 128 + pc * 8]);
        sacc[0][nk] = __builtin_amdgcn_mfma_f32_16x16x32_bf16(qf[0][ks], kf, sacc[0][nk], 0, 0, 0);
        sacc[1][nk] = __builtin_amdgcn_mfma_f32_16x16x32_bf16(qf[1][ks], kf, sacc[1][nk], 0, 0, 0);
      }
    }

    const bool needMask = (kt * 64 + 63) > q0;
#pragma unroll
    for (int mq = 0; mq < 2; ++mq)
#pragma unroll
      for (int nk = 0; nk < 4; ++nk)
#pragma unroll
        for (int r = 0; r < 4; ++r) {
          float sv = sacc[mq][nk][r] * SCALE;
          if (needMask && (kt * 64 + nk * 16 + lr) > (q0 + mq * 16 + lg * 4 + r)) sv = -1e30f;
          sacc[mq][nk][r] = sv;
        }

    // online softmax (rows replicated across the 16 lanes of each row group)
    float alpha[2][4], rsum[2][4];
#pragma unroll
    for (int mq = 0; mq < 2; ++mq)
#pragma unroll
      for (int r = 0; r < 4; ++r) {
        float pm = fmaxf(fmaxf(sacc[mq][0][r], sacc[mq][1][r]),
                         fmaxf(sacc[mq][2][r], sacc[mq][3][r]));
        pm = fmaxf(pm, __shfl_xor(pm, 1));
        pm = fmaxf(pm, __shfl_xor(pm, 2));
        pm = fmaxf(pm, __shfl_xor(pm, 4));
        pm = fmaxf(pm, __shfl_xor(pm, 8));
        float mnew = fmaxf(m_run[mq][r], pm);
        alpha[mq][r] = __expf(m_run[mq][r] - mnew);
        m_run[mq][r] = mnew;
        rsum[mq][r] = 0.f;
      }

#pragma unroll
    for (int mq = 0; mq < 2; ++mq)
#pragma unroll
      for (int nk = 0; nk < 4; ++nk) {
        int key = nk * 16 + lr;
#pragma unroll
        for (int r = 0; r < 4; ++r) {
          float p = __expf(sacc[mq][nk][r] - m_run[mq][r]);
          rsum[mq][r] += p;
          int qrow = mq * 16 + lg * 4 + r;
          int pcw = (key >> 3) ^ (qrow & 7);
          Pw[qrow * 64 + pcw * 8 + (key & 7)] = f2bf(p);
        }
      }

#pragma unroll
    for (int mq = 0; mq < 2; ++mq)
#pragma unroll
      for (int r = 0; r < 4; ++r) {
        float rs = rsum[mq][r];
        rs += __shfl_xor(rs, 1);
        rs += __shfl_xor(rs, 2);
        rs += __shfl_xor(rs, 4);
        rs += __shfl_xor(rs, 8);
        l_run[mq][r] = l_run[mq][r] * alpha[mq][r] + rs;
      }

#pragma unroll
    for (int mq = 0; mq < 2; ++mq)
#pragma unroll
      for (int nd = 0; nd < 8; ++nd)
#pragma unroll
        for (int r = 0; r < 4; ++r) o_acc[mq][nd][r] *= alpha[mq][r];

    // O += P @ V
#pragma unroll
    for (int kk = 0; kk < 2; ++kk) {
      v8bf pa[2];
#pragma unroll
      for (int mq = 0; mq < 2; ++mq) {
        int q = mq * 16 + lr;
        int pc = (kk * 4 + lg) ^ (q & 7);
        pa[mq] = *(const v8bf*)(&Pw[q * 64 + pc * 8]);
      }
#pragma unroll
      for (int nd = 0; nd < 8; ++nd) {
        int d = nd * 16 + lr;
        int pc = (kk * 4 + lg) ^ (d & 7);
        v8bf vb = *(const v8bf*)(&Vs[d * 64 + pc * 8]);
        o_acc[0][nd] = __builtin_amdgcn_mfma_f32_16x16x32_bf16(pa[0], vb, o_acc[0][nd], 0, 0, 0);
        o_acc[1][nd] = __builtin_amdgcn_mfma_f32_16x16x32_bf16(pa[1], vb, o_acc[1][nd], 0, 0, 0);
      }
    }
  }

  const int b = bh >> 5, h = bh & 31;
#pragma unroll
  for (int mq = 0; mq < 2; ++mq)
#pragma unroll
    for (int r = 0; r < 4; ++r) {
      int srow = q0 + mq * 16 + lg * 4 + r;
      float inv = 1.f / l_run[mq][r];
      us* orow = Out + ((long)b * 1024 + srow) * 4096 + h * 128;
#pragma unroll
      for (int nd = 0; nd < 8; ++nd) orow[nd * 16 + lr] = f2bf(o_acc[mq][nd][r] * inv);
    }
}

// ---------------- launcher ----------------
// ws layout (bytes), peak 224 MB with reuse:
//  [0,   32M)  hidden_bf16  -> reused as Vt after QKV GEMM
//  [32M, 128M) wqkv_bf16    -> reused as attn_bf16 [32M,64M) + wo_bf16 [64M,96M)
//  [128M,160M) Q  [160M,192M) K  [192M,224M) V     (all [b][h][s][d])
extern "C" void kernel_launch(void* const* d_in, const int* in_sizes, int n_in,
                              void* d_out, int out_size, void* d_ws, size_t ws_size,
                              hipStream_t stream) {
  const float* hidden = (const float*)d_in[0];
  const float* cosT = (const float*)d_in[1];
  const float* sinT = (const float*)d_in[2];
  const float* wqkv = (const float*)d_in[3];
  const float* wo = (const float*)d_in[4];
  float* out = (float*)d_out;
  char* ws = (char*)d_ws;

  us* hB = (us*)(ws);
  us* wqB = (us*)(ws + 33554432ull);
  us* Qb = (us*)(ws + 134217728ull);
  us* Kb = (us*)(ws + 167772160ull);
  us* Vb = (us*)(ws + 201326592ull);
  us* VtB = (us*)(ws);                  // reuse hidden_bf16 region
  us* atB = (us*)(ws + 33554432ull);    // reuse wqkv_bf16 region
  us* woB = (us*)(ws + 67108864ull);    // reuse wqkv_bf16 region (2nd third)

  cast_kernel<<<2048, 256, 0, stream>>>(hidden, hB, 4096 * 4096);
  cast_kernel<<<2048, 256, 0, stream>>>(wqkv, wqB, 12288 * 4096);
  gemm_bt<1><<<dim3(96, 32), 256, 0, stream>>>(hB, wqB, 4096, 12288, 4096,
                                               nullptr, Qb, Kb, Vb);
  rope_kernel<<<16384, 256, 0, stream>>>(Qb, Kb, cosT, sinT);
  transpose_v<<<dim3(16, 2, 128), 256, 0, stream>>>(Vb, VtB);
  cast_kernel<<<2048, 256, 0, stream>>>(wo, woB, 4096 * 4096);
  attn_kernel<<<dim3(8, 128), 256, 0, stream>>>(Qb, Kb, VtB, atB);
  gemm_bt<0><<<dim3(32, 32), 256, 0, stream>>>(atB, woB, 4096, 4096, 4096,
                                               out, nullptr, nullptr, nullptr);
}

// Round 2
// 755.269 us; speedup vs baseline: 1.2267x; 1.2267x over previous
//
#include <hip/hip_runtime.h>

typedef unsigned short us;
typedef __bf16 v8bf __attribute__((ext_vector_type(8)));
typedef float v4f __attribute__((ext_vector_type(4)));
typedef us us4v __attribute__((ext_vector_type(4)));
typedef us us8v __attribute__((ext_vector_type(8)));
typedef float f4v __attribute__((ext_vector_type(4)));

#define SCALE 0.08838834764831845f

__device__ __forceinline__ us f2bf(float f) {
  unsigned u = __builtin_bit_cast(unsigned, f);
  u += 0x7fffu + ((u >> 16) & 1u);
  return (us)(u >> 16);
}
__device__ __forceinline__ float bf2f(us h) {
  unsigned u = ((unsigned)h) << 16;
  return __builtin_bit_cast(float, u);
}

typedef const __attribute__((address_space(1))) void* gas_t;
typedef __attribute__((address_space(3))) void* las_t;
#define GLD16(gp, lp) __builtin_amdgcn_global_load_lds((gas_t)(gp), (las_t)(lp), 16, 0, 0)

// ---------------- fp32 -> bf16 cast (vectorized, grid-stride) ----------------
__global__ void cast_kernel(const float* __restrict__ in, us* __restrict__ out, int n) {
  int stride = gridDim.x * blockDim.x * 4;
  for (int i = (blockIdx.x * blockDim.x + threadIdx.x) * 4; i < n; i += stride) {
    f4v f = *(const f4v*)(in + i);
    us4v o;
#pragma unroll
    for (int j = 0; j < 4; ++j) o[j] = f2bf(f[j]);
    *(us4v*)(out + i) = o;
  }
}

// ---------------- 256x256 8-phase GEMM: C = A @ Bt^T ----------------
// A[M,K], Bt[N,K] row-major bf16. BK=64, 8 waves (2Mx4N), per-wave 128x64 out.
// LDS 128 KiB: 2 buffers x (A 256x64 + B 256x64) bf16, 16B-chunk XOR swizzle
// (chunk ^= row&7), staged via global_load_lds with inverse-swizzled source.
// T3+T4: 4 phases/K-tile, counted vmcnt (4 in flight across tile boundary).
// EPI 0: fp32 write to outF[M,N]. EPI 1: bf16 scatter to Q/K/V [b][h][s][d].
template <int EPI>
__global__ __launch_bounds__(512, 2) void gemm8(
    const us* __restrict__ A, const us* __restrict__ Bt, int M, int N, int K,
    float* __restrict__ outF, us* __restrict__ outQ, us* __restrict__ outK,
    us* __restrict__ outV, int MT) {
  __shared__ us lds[65536];  // [2 buf][A 16384 | B 16384]
  const int tid = threadIdx.x, lane = tid & 63, w = tid >> 6;
  const int nwg = gridDim.x;
  const int bid = blockIdx.x;
  const int cpx = nwg >> 3;
  const int swz = (bid & 7) * cpx + (bid >> 3);  // grids are %8==0 (768, 256)
  const int bm = swz % MT, bn = swz / MT;
  const int row0 = bm * 256, col0 = bn * 256;
  const int wr = w >> 2, wc = w & 3;
  const int lr = lane & 15, lg = lane >> 4;
  const int NTK = K >> 6;

// stage round j (of 4) of tile t's A/B panel into buffer p.
// chunk q = j*512+tid: LDS row q>>3, physical chunk q&7; global column-chunk
// is (q&7)^(row&7) so that a swizzled read returns logical data.
#define STAGE_A(t, p, j)                                                      \
  do {                                                                        \
    int q_ = (j) * 512 + tid;                                                 \
    int row_ = q_ >> 3, cph_ = q_ & 7;                                        \
    GLD16(A + (long)(row0 + row_) * K + (t) * 64 + ((cph_ ^ (row_ & 7)) * 8), \
          &lds[(p) * 32768 + ((j) * 512 + w * 64) * 8]);                      \
  } while (0)
#define STAGE_B(t, p, j)                                                      \
  do {                                                                        \
    int q_ = (j) * 512 + tid;                                                 \
    int row_ = q_ >> 3, cph_ = q_ & 7;                                        \
    GLD16(Bt + (long)(col0 + row_) * K + (t) * 64 + ((cph_ ^ (row_ & 7)) * 8),\
          &lds[(p) * 32768 + 16384 + ((j) * 512 + w * 64) * 8]);              \
  } while (0)

  v4f acc[8][4];
#pragma unroll
  for (int m = 0; m < 8; ++m)
#pragma unroll
    for (int n = 0; n < 4; ++n)
#pragma unroll
      for (int j = 0; j < 4; ++j) acc[m][n][j] = 0.f;

  // prologue: tile0 (A+B) into buf0, tile1's A into buf1; keep 4 in flight
  STAGE_A(0, 0, 0); STAGE_A(0, 0, 1); STAGE_A(0, 0, 2); STAGE_A(0, 0, 3);
  STAGE_B(0, 0, 0); STAGE_B(0, 0, 1); STAGE_B(0, 0, 2); STAGE_B(0, 0, 3);
  if (NTK > 1) {
    STAGE_A(1, 1, 0); STAGE_A(1, 1, 1); STAGE_A(1, 1, 2); STAGE_A(1, 1, 3);
    asm volatile("s_waitcnt vmcnt(4)" ::: "memory");
  } else {
    asm volatile("s_waitcnt vmcnt(0)" ::: "memory");
  }
  __builtin_amdgcn_s_barrier();

  for (int t = 0; t < NTK; ++t) {
    const int p = t & 1;
    const int pb = p ^ 1;
    const us* Abase = &lds[p * 32768];
    const us* Bbase = &lds[p * 32768 + 16384];
    v8bf bfr[4][2];
#pragma unroll
    for (int ph = 0; ph < 4; ++ph) {
      if (ph == 0) {
#pragma unroll
        for (int n = 0; n < 4; ++n)
#pragma unroll
          for (int kk = 0; kk < 2; ++kk)
            bfr[n][kk] = *(const v8bf*)&Bbase[(wc * 64 + n * 16 + lr) * 64 +
                                              (((kk * 4 + lg) ^ (lr & 7)) * 8)];
      }
      v8bf af[2][2];
#pragma unroll
      for (int mm = 0; mm < 2; ++mm)
#pragma unroll
        for (int kk = 0; kk < 2; ++kk)
          af[mm][kk] = *(const v8bf*)&Abase[(wr * 128 + ph * 32 + mm * 16 + lr) * 64 +
                                            (((kk * 4 + lg) ^ (lr & 7)) * 8)];
      if (ph == 0 && t + 1 < NTK) { STAGE_B(t + 1, pb, 0); STAGE_B(t + 1, pb, 1); }
      if (ph == 1 && t + 1 < NTK) { STAGE_B(t + 1, pb, 2); STAGE_B(t + 1, pb, 3); }
      __builtin_amdgcn_s_barrier();
      asm volatile("s_waitcnt lgkmcnt(0)" ::: "memory");
      __builtin_amdgcn_s_setprio(1);
#pragma unroll
      for (int kk = 0; kk < 2; ++kk)
#pragma unroll
        for (int mm = 0; mm < 2; ++mm)
#pragma unroll
          for (int n = 0; n < 4; ++n)
            acc[ph * 2 + mm][n] = __builtin_amdgcn_mfma_f32_16x16x32_bf16(
                af[mm][kk], bfr[n][kk], acc[ph * 2 + mm][n], 0, 0, 0);
      __builtin_amdgcn_s_setprio(0);
      __builtin_amdgcn_s_barrier();
    }
    // tile boundary: buf p fully consumed (post-MFMA barrier passed by all
    // waves) -> issue A(t+2) into it, then wait for tile t+1 (leave 4 in flight)
    if (t + 2 < NTK) {
      STAGE_A(t + 2, p, 0); STAGE_A(t + 2, p, 1);
      STAGE_A(t + 2, p, 2); STAGE_A(t + 2, p, 3);
      asm volatile("s_waitcnt vmcnt(4)" ::: "memory");
    } else if (t + 1 < NTK) {
      asm volatile("s_waitcnt vmcnt(0)" ::: "memory");
    }
    __builtin_amdgcn_s_barrier();
  }
#undef STAGE_A
#undef STAGE_B

  if (EPI == 0) {
#pragma unroll
    for (int m = 0; m < 8; ++m) {
#pragma unroll
      for (int r = 0; r < 4; ++r) {
        int row = row0 + wr * 128 + m * 16 + lg * 4 + r;
#pragma unroll
        for (int n = 0; n < 4; ++n) {
          int col = col0 + wc * 64 + n * 16 + lr;
          outF[(long)row * N + col] = acc[m][n][r];
        }
      }
    }
  } else {
    const int colbase = col0 + wc * 64;          // multiple of 64
    const int which = colbase >> 12;             // 0=Q 1=K 2=V
    const int h = (colbase >> 7) & 31;
    const int d0 = colbase & 127;                // 0 or 64
    us* base = (which == 0) ? outQ : ((which == 1) ? outK : outV);
#pragma unroll
    for (int m = 0; m < 8; ++m) {
#pragma unroll
      for (int r = 0; r < 4; ++r) {
        int trow = row0 + wr * 128 + m * 16 + lg * 4 + r;
        int b2 = trow >> 10, spos = trow & 1023;
        us* rowp = base + ((b2 * 32 + h) * 1024 + spos) * 128 + d0;
#pragma unroll
        for (int n = 0; n < 4; ++n) rowp[n * 16 + lr] = f2bf(acc[m][n][r]);
      }
    }
  }
}

// ---------------- RoPE in place on Q and K ([b][h][s][d] bf16) ----------------
__global__ void rope_kernel(us* __restrict__ Qb, us* __restrict__ Kb,
                            const float* __restrict__ cosT, const float* __restrict__ sinT) {
  int idx = blockIdx.x * blockDim.x + threadIdx.x;  // 2 * 131072 rows * 16 thr/row
  int pj = idx & 15;
  int rowid = idx >> 4;
  us* P = (rowid < 131072) ? Qb : Kb;
  int r = rowid & 131071;
  int bh = r >> 10, spos = r & 1023;
  int b = bh >> 5;
  int t = b * 1024 + spos;
  int d0 = pj * 4;
  us* p = P + (long)r * 128;
  us4v x1 = *(const us4v*)(p + d0);
  us4v x2 = *(const us4v*)(p + d0 + 64);
  f4v c = *(const f4v*)(cosT + t * 64 + d0);
  f4v s = *(const f4v*)(sinT + t * 64 + d0);
  us4v y1, y2;
#pragma unroll
  for (int j = 0; j < 4; ++j) {
    float a = bf2f(x1[j]), bv = bf2f(x2[j]);
    y1[j] = f2bf(a * c[j] - bv * s[j]);
    y2[j] = f2bf(bv * c[j] + a * s[j]);
  }
  *(us4v*)(p + d0) = y1;
  *(us4v*)(p + d0 + 64) = y2;
}

// ---------------- V transpose: [bh][s][d] -> [bh][d][s] ----------------
__global__ void transpose_v(const us* __restrict__ V, us* __restrict__ Vt) {
  __shared__ us tile[64][66];
  const int tid = threadIdx.x;
  const int s0 = blockIdx.x * 64;
  const int d0 = blockIdx.y * 64;
  const int bh = blockIdx.z;
  const us* Vb = V + (long)bh * 131072;
  us* Vtb = Vt + (long)bh * 131072;
  const int rr = tid >> 2, cq = tid & 3;
  us8v v0 = *(const us8v*)(Vb + (s0 + rr) * 128 + d0 + cq * 16);
  us8v v1 = *(const us8v*)(Vb + (s0 + rr) * 128 + d0 + cq * 16 + 8);
#pragma unroll
  for (int j = 0; j < 8; ++j) {
    tile[rr][cq * 16 + j] = v0[j];
    tile[rr][cq * 16 + 8 + j] = v1[j];
  }
  __syncthreads();
  us8v o0, o1;
#pragma unroll
  for (int j = 0; j < 8; ++j) {
    o0[j] = tile[cq * 16 + j][rr];
    o1[j] = tile[cq * 16 + 8 + j][rr];
  }
  *(us8v*)(Vtb + (d0 + rr) * 1024 + s0 + cq * 16) = o0;
  *(us8v*)(Vtb + (d0 + rr) * 1024 + s0 + cq * 16 + 8) = o1;
}

// ---------------- causal flash attention ----------------
__global__ __launch_bounds__(256, 2) void attn_kernel(
    const us* __restrict__ Q, const us* __restrict__ Kg,
    const us* __restrict__ Vt, us* __restrict__ Out) {
  __shared__ us Ks[8192];
  __shared__ us Vs[8192];
  __shared__ us Ps[4 * 2048];
  const int tid = threadIdx.x, lane = tid & 63, w = tid >> 6;
  const int qt = (int)gridDim.x - 1 - (int)blockIdx.x;
  const int bh = blockIdx.y;
  const int lr = lane & 15, lg = lane >> 4;
  const int q0 = qt * 128 + w * 32;

  v8bf qf[2][4];
  const us* Qb = Q + ((long)bh * 1024 + q0) * 128;
#pragma unroll
  for (int mq = 0; mq < 2; ++mq)
#pragma unroll
    for (int ks = 0; ks < 4; ++ks)
      qf[mq][ks] = *(const v8bf*)(Qb + (mq * 16 + lr) * 128 + ks * 32 + lg * 8);

  float m_run[2][4], l_run[2][4];
  v4f o_acc[2][8];
#pragma unroll
  for (int mq = 0; mq < 2; ++mq) {
#pragma unroll
    for (int r = 0; r < 4; ++r) {
      m_run[mq][r] = -1e30f;
      l_run[mq][r] = 0.f;
    }
#pragma unroll
    for (int nd = 0; nd < 8; ++nd)
#pragma unroll
      for (int j = 0; j < 4; ++j) o_acc[mq][nd][j] = 0.f;
  }

  const us* Kbase = Kg + (long)bh * 131072;
  const us* Vbase = Vt + (long)bh * 131072;
  us* Pw = &Ps[w * 2048];

  const int nkt = 2 * qt + 2;
  for (int kt = 0; kt < nkt; ++kt) {
    __syncthreads();
#pragma unroll
    for (int i = 0; i < 4; ++i) {
      int c = (i * 4 + w) * 64 + lane;
      int rk = c >> 4, pc = c & 15;
      GLD16(Kbase + (kt * 64 + rk) * 128 + ((pc ^ (rk & 7)) * 8), &Ks[(i * 4 + w) * 512]);
    }
#pragma unroll
    for (int i = 0; i < 4; ++i) {
      int c = (i * 4 + w) * 64 + lane;
      int dd = c >> 3, pc = c & 7;
      GLD16(Vbase + dd * 1024 + kt * 64 + ((pc ^ (dd & 7)) * 8), &Vs[(i * 4 + w) * 512]);
    }
    __syncthreads();

    v4f sacc[2][4];
#pragma unroll
    for (int mq = 0; mq < 2; ++mq)
#pragma unroll
      for (int nk = 0; nk < 4; ++nk)
#pragma unroll
        for (int j = 0; j < 4; ++j) sacc[mq][nk][j] = 0.f;
#pragma unroll
    for (int nk = 0; nk < 4; ++nk) {
      int key = nk * 16 + lr;
#pragma unroll
      for (int ks = 0; ks < 4; ++ks) {
        int pc = (ks * 4 + lg) ^ (key & 7);
        v8bf kf = *(const v8bf*)(&Ks[key * 128 + pc * 8]);
        sacc[0][nk] = __builtin_amdgcn_mfma_f32_16x16x32_bf16(qf[0][ks], kf, sacc[0][nk], 0, 0, 0);
        sacc[1][nk] = __builtin_amdgcn_mfma_f32_16x16x32_bf16(qf[1][ks], kf, sacc[1][nk], 0, 0, 0);
      }
    }

    const bool needMask = (kt * 64 + 63) > q0;
#pragma unroll
    for (int mq = 0; mq < 2; ++mq)
#pragma unroll
      for (int nk = 0; nk < 4; ++nk)
#pragma unroll
        for (int r = 0; r < 4; ++r) {
          float sv = sacc[mq][nk][r] * SCALE;
          if (needMask && (kt * 64 + nk * 16 + lr) > (q0 + mq * 16 + lg * 4 + r)) sv = -1e30f;
          sacc[mq][nk][r] = sv;
        }

    float alpha[2][4], rsum[2][4];
#pragma unroll
    for (int mq = 0; mq < 2; ++mq)
#pragma unroll
      for (int r = 0; r < 4; ++r) {
        float pm = fmaxf(fmaxf(sacc[mq][0][r], sacc[mq][1][r]),
                         fmaxf(sacc[mq][2][r], sacc[mq][3][r]));
        pm = fmaxf(pm, __shfl_xor(pm, 1));
        pm = fmaxf(pm, __shfl_xor(pm, 2));
        pm = fmaxf(pm, __shfl_xor(pm, 4));
        pm = fmaxf(pm, __shfl_xor(pm, 8));
        float mnew = fmaxf(m_run[mq][r], pm);
        alpha[mq][r] = __expf(m_run[mq][r] - mnew);
        m_run[mq][r] = mnew;
        rsum[mq][r] = 0.f;
      }

#pragma unroll
    for (int mq = 0; mq < 2; ++mq)
#pragma unroll
      for (int nk = 0; nk < 4; ++nk) {
        int key = nk * 16 + lr;
#pragma unroll
        for (int r = 0; r < 4; ++r) {
          float p = __expf(sacc[mq][nk][r] - m_run[mq][r]);
          rsum[mq][r] += p;
          int qrow = mq * 16 + lg * 4 + r;
          int pcw = (key >> 3) ^ (qrow & 7);
          Pw[qrow * 64 + pcw * 8 + (key & 7)] = f2bf(p);
        }
      }

#pragma unroll
    for (int mq = 0; mq < 2; ++mq)
#pragma unroll
      for (int r = 0; r < 4; ++r) {
        float rs = rsum[mq][r];
        rs += __shfl_xor(rs, 1);
        rs += __shfl_xor(rs, 2);
        rs += __shfl_xor(rs, 4);
        rs += __shfl_xor(rs, 8);
        l_run[mq][r] = l_run[mq][r] * alpha[mq][r] + rs;
      }

#pragma unroll
    for (int mq = 0; mq < 2; ++mq)
#pragma unroll
      for (int nd = 0; nd < 8; ++nd)
#pragma unroll
        for (int r = 0; r < 4; ++r) o_acc[mq][nd][r] *= alpha[mq][r];

#pragma unroll
    for (int kk = 0; kk < 2; ++kk) {
      v8bf pa[2];
#pragma unroll
      for (int mq = 0; mq < 2; ++mq) {
        int q = mq * 16 + lr;
        int pc = (kk * 4 + lg) ^ (q & 7);
        pa[mq] = *(const v8bf*)(&Pw[q * 64 + pc * 8]);
      }
#pragma unroll
      for (int nd = 0; nd < 8; ++nd) {
        int d = nd * 16 + lr;
        int pc = (kk * 4 + lg) ^ (d & 7);
        v8bf vb = *(const v8bf*)(&Vs[d * 64 + pc * 8]);
        o_acc[0][nd] = __builtin_amdgcn_mfma_f32_16x16x32_bf16(pa[0], vb, o_acc[0][nd], 0, 0, 0);
        o_acc[1][nd] = __builtin_amdgcn_mfma_f32_16x16x32_bf16(pa[1], vb, o_acc[1][nd], 0, 0, 0);
      }
    }
  }

  const int b = bh >> 5, h = bh & 31;
#pragma unroll
  for (int mq = 0; mq < 2; ++mq)
#pragma unroll
    for (int r = 0; r < 4; ++r) {
      int srow = q0 + mq * 16 + lg * 4 + r;
      float inv = 1.f / l_run[mq][r];
      us* orow = Out + ((long)b * 1024 + srow) * 4096 + h * 128;
#pragma unroll
      for (int nd = 0; nd < 8; ++nd) orow[nd * 16 + lr] = f2bf(o_acc[mq][nd][r] * inv);
    }
}

// ---------------- launcher ----------------
extern "C" void kernel_launch(void* const* d_in, const int* in_sizes, int n_in,
                              void* d_out, int out_size, void* d_ws, size_t ws_size,
                              hipStream_t stream) {
  const float* hidden = (const float*)d_in[0];
  const float* cosT = (const float*)d_in[1];
  const float* sinT = (const float*)d_in[2];
  const float* wqkv = (const float*)d_in[3];
  const float* wo = (const float*)d_in[4];
  float* out = (float*)d_out;
  char* ws = (char*)d_ws;

  us* hB = (us*)(ws);
  us* wqB = (us*)(ws + 33554432ull);
  us* Qb = (us*)(ws + 134217728ull);
  us* Kb = (us*)(ws + 167772160ull);
  us* Vb = (us*)(ws + 201326592ull);
  us* VtB = (us*)(ws);                  // reuse hidden_bf16 region
  us* atB = (us*)(ws + 33554432ull);    // reuse wqkv_bf16 region
  us* woB = (us*)(ws + 67108864ull);    // reuse wqkv_bf16 region (2nd third)

  cast_kernel<<<2048, 256, 0, stream>>>(hidden, hB, 4096 * 4096);
  cast_kernel<<<2048, 256, 0, stream>>>(wqkv, wqB, 12288 * 4096);
  gemm8<1><<<768, 512, 0, stream>>>(hB, wqB, 4096, 12288, 4096,
                                    nullptr, Qb, Kb, Vb, 16);
  rope_kernel<<<16384, 256, 0, stream>>>(Qb, Kb, cosT, sinT);
  transpose_v<<<dim3(16, 2, 128), 256, 0, stream>>>(Vb, VtB);
  cast_kernel<<<2048, 256, 0, stream>>>(wo, woB, 4096 * 4096);
  attn_kernel<<<dim3(8, 128), 256, 0, stream>>>(Qb, Kb, VtB, atB);
  gemm8<0><<<256, 512, 0, stream>>>(atB, woB, 4096, 4096, 4096,
                                    out, nullptr, nullptr, nullptr, 16);
}